// Round 9
// baseline (218.966 us; speedup 1.0000x reference)
//
#include <hip/hip_runtime.h>
#include <math.h>

// L2ClusterCentroid: N=1e6 rows, D=128, C=100.
// assign = argmax(logits, -1); centroids = segment_mean(embedding, assign);
// out[c] = counts[c]>0 ? ||centers[c] - centroids[c]||_2 : 0
//
// Round-9: total 191us; decomposition says K1 argmax ~95us (4.2 TB/s) is the
// remaining inefficiency (gather ~90us is near gather ceiling; floor ~136us).
// K1 changes: 2 rows per quad (14 loads in flight/lane, 2x MLP), fmax-tree +
// index-recovery (chain depth ~10 vs ~50), nontemporal loads on the big
// streams (logits, embedding) to keep assign cache-resident for K2.

#define NROWS 1000000
#define DIM   128
#define NCLS  100
#define NSLICE 16
#define SLICE_ROWS (NROWS / NSLICE)   // 62500
#define PSTRIDE (DIM + 2)             // 130 floats (even -> float2-aligned)
#define QCAP  128
#define QMASK 127
#define DRAINN 16

typedef __attribute__((ext_vector_type(4))) float f32x4;
typedef __attribute__((ext_vector_type(2))) float f32x2;

// ---------------- K1: argmax over logits rows ----------------
__device__ __forceinline__ void row_argmax(const f32x4 v[6], float t, int p,
                                           int row, int* __restrict__ assign)
{
    // per-lane max over this lane's 25 cols (tree, depth 3)
    float m0 = fmaxf(fmaxf(v[0][0], v[0][1]), fmaxf(v[0][2], v[0][3]));
    float m1 = fmaxf(fmaxf(v[1][0], v[1][1]), fmaxf(v[1][2], v[1][3]));
    float m2 = fmaxf(fmaxf(v[2][0], v[2][1]), fmaxf(v[2][2], v[2][3]));
    float m3 = fmaxf(fmaxf(v[3][0], v[3][1]), fmaxf(v[3][2], v[3][3]));
    float m4 = fmaxf(fmaxf(v[4][0], v[4][1]), fmaxf(v[4][2], v[4][3]));
    float m5 = fmaxf(fmaxf(v[5][0], v[5][1]), fmaxf(v[5][2], v[5][3]));
    float mm = fmaxf(fmaxf(fmaxf(m0, m1), fmaxf(m2, m3)),
                     fmaxf(fmaxf(m4, m5), t));
    // quad value-merge (quad_perm DPP)
    mm = fmaxf(mm, __shfl_xor(mm, 1, 64));
    mm = fmaxf(mm, __shfl_xor(mm, 2, 64));
    // first index equal to max: min over matching cols (independent cmps)
    int bi = 0x7fffffff;
    #pragma unroll
    for (int i = 0; i < 6; ++i) {
        #pragma unroll
        for (int j = 0; j < 4; ++j) {
            const int col = 16 * i + 4 * p + j;
            if (v[i][j] == mm) bi = min(bi, col);
        }
    }
    if (t == mm) bi = min(bi, 96 + p);
    bi = min(bi, __shfl_xor(bi, 1, 64));
    bi = min(bi, __shfl_xor(bi, 2, 64));
    if (p == 0) assign[row] = bi;
}

__global__ __launch_bounds__(256)
void l2cc_argmax(const float* __restrict__ logits, int* __restrict__ assign)
{
    const int g = threadIdx.x >> 2;       // quad id 0..63
    const int p = threadIdx.x & 3;
    const int row0 = blockIdx.x * 128 + g * 2;   // 2 consecutive rows per quad
    if (row0 >= NROWS) return;                   // NROWS even -> row0+1 safe

    const f32x4* lr0 = reinterpret_cast<const f32x4*>(logits + (size_t)row0 * NCLS);
    const f32x4* lr1 = reinterpret_cast<const f32x4*>(logits + (size_t)(row0 + 1) * NCLS);

    f32x4 va[6], vb[6];
    #pragma unroll
    for (int i = 0; i < 6; ++i) va[i] = __builtin_nontemporal_load(&lr0[i * 4 + p]);
    #pragma unroll
    for (int i = 0; i < 6; ++i) vb[i] = __builtin_nontemporal_load(&lr1[i * 4 + p]);
    const float ta = __builtin_nontemporal_load(logits + (size_t)row0 * NCLS + 96 + p);
    const float tb = __builtin_nontemporal_load(logits + (size_t)(row0 + 1) * NCLS + 96 + p);

    row_argmax(va, ta, p, row0,     assign);
    row_argmax(vb, tb, p, row0 + 1, assign);
}

// ---------------- K2: scan + queued batch-gather ----------------
#define LDROW(R) __builtin_nontemporal_load(                                  \
    reinterpret_cast<const f32x2*>(emb + (size_t)(R) * DIM + lane * 2))

#define DRAIN16                                                              \
    {                                                                        \
        const int i0  = q[wave][(qhead+ 0)&QMASK], i1  = q[wave][(qhead+ 1)&QMASK]; \
        const int i2  = q[wave][(qhead+ 2)&QMASK], i3  = q[wave][(qhead+ 3)&QMASK]; \
        const int i4  = q[wave][(qhead+ 4)&QMASK], i5  = q[wave][(qhead+ 5)&QMASK]; \
        const int i6  = q[wave][(qhead+ 6)&QMASK], i7  = q[wave][(qhead+ 7)&QMASK]; \
        const int i8  = q[wave][(qhead+ 8)&QMASK], i9  = q[wave][(qhead+ 9)&QMASK]; \
        const int i10 = q[wave][(qhead+10)&QMASK], i11 = q[wave][(qhead+11)&QMASK]; \
        const int i12 = q[wave][(qhead+12)&QMASK], i13 = q[wave][(qhead+13)&QMASK]; \
        const int i14 = q[wave][(qhead+14)&QMASK], i15 = q[wave][(qhead+15)&QMASK]; \
        const f32x2 e0 = LDROW(i0),  e1 = LDROW(i1),  e2 = LDROW(i2),  e3 = LDROW(i3); \
        const f32x2 e4 = LDROW(i4),  e5 = LDROW(i5),  e6 = LDROW(i6),  e7 = LDROW(i7); \
        const f32x2 e8 = LDROW(i8),  e9 = LDROW(i9),  e10= LDROW(i10), e11= LDROW(i11);\
        const f32x2 e12= LDROW(i12), e13= LDROW(i13), e14= LDROW(i14), e15= LDROW(i15);\
        ax += e0[0];  ay += e0[1];  ax += e1[0];  ay += e1[1];               \
        ax += e2[0];  ay += e2[1];  ax += e3[0];  ay += e3[1];               \
        ax += e4[0];  ay += e4[1];  ax += e5[0];  ay += e5[1];               \
        ax += e6[0];  ay += e6[1];  ax += e7[0];  ay += e7[1];               \
        ax += e8[0];  ay += e8[1];  ax += e9[0];  ay += e9[1];               \
        ax += e10[0]; ay += e10[1]; ax += e11[0]; ay += e11[1];              \
        ax += e12[0]; ay += e12[1]; ax += e13[0]; ay += e13[1];              \
        ax += e14[0]; ay += e14[1]; ax += e15[0]; ay += e15[1];              \
        qhead += 16;                                                         \
    }

#define PUSH(AV, OFF)                                                        \
    {                                                                        \
        const unsigned long long m_ = __ballot((AV) == c);                   \
        if ((AV) == c) {                                                     \
            const int rank_ = __popcll(m_ & ((1ull << lane) - 1ull));        \
            q[wave][(qtail + rank_) & QMASK] = rw + (OFF) + lane;            \
        }                                                                    \
        const int pc_ = __popcll(m_);                                        \
        qtail += pc_; icnt += pc_;                                           \
        while (qtail - qhead >= DRAINN) DRAIN16                              \
    }

__global__ __launch_bounds__(256)
void l2cc_gather(const float* __restrict__ emb,
                 const int* __restrict__ assign,
                 float* __restrict__ partial)
{
    const int bid  = blockIdx.x;
    const int c    = bid / NSLICE;       // cluster this block owns
    const int sl   = bid - c * NSLICE;   // row-slice
    const int wave = threadIdx.x >> 6;
    const int lane = threadIdx.x & 63;

    __shared__ int   q[4][QCAP];         // per-wave matched-row-id ring
    __shared__ float sx[4][64], sy[4][64];
    __shared__ int   scnt[4];

    const int start = sl * SLICE_ROWS;
    const int end   = start + SLICE_ROWS;

    float ax = 0.0f, ay = 0.0f;
    int   icnt = 0, qhead = 0, qtail = 0;

    int rw = start + wave * 256;
    int a0 = (rw +   0 + lane < end) ? assign[rw +   0 + lane] : -1;
    int a1 = (rw +  64 + lane < end) ? assign[rw +  64 + lane] : -1;
    int a2 = (rw + 128 + lane < end) ? assign[rw + 128 + lane] : -1;
    int a3 = (rw + 192 + lane < end) ? assign[rw + 192 + lane] : -1;

    for (; rw < end; rw += 1024) {
        const int rn = rw + 1024;        // prefetch next 256-row group
        int b0 = -1, b1 = -1, b2 = -1, b3 = -1;
        if (rn < end) {
            b0 = (rn +   0 + lane < end) ? assign[rn +   0 + lane] : -1;
            b1 = (rn +  64 + lane < end) ? assign[rn +  64 + lane] : -1;
            b2 = (rn + 128 + lane < end) ? assign[rn + 128 + lane] : -1;
            b3 = (rn + 192 + lane < end) ? assign[rn + 192 + lane] : -1;
        }

        PUSH(a0, 0) PUSH(a1, 64) PUSH(a2, 128) PUSH(a3, 192)

        a0 = b0; a1 = b1; a2 = b2; a3 = b3;
    }

    // tail: drain remaining queued rows one at a time (fixed order)
    while (qtail > qhead) {
        const int r = q[wave][qhead & QMASK]; ++qhead;
        const f32x2 e = LDROW(r);
        ax += e[0]; ay += e[1];
    }

    // cross-wave reduce (fixed order, deterministic)
    sx[wave][lane] = ax;
    sy[wave][lane] = ay;
    if (lane == 0) scnt[wave] = icnt;
    __syncthreads();
    if (wave == 0) {
        const float fx = ((sx[0][lane] + sx[1][lane]) + sx[2][lane]) + sx[3][lane];
        const float fy = ((sy[0][lane] + sy[1][lane]) + sy[2][lane]) + sy[3][lane];
        float* p = partial + (size_t)bid * PSTRIDE;
        reinterpret_cast<float2*>(p)[lane] = make_float2(fx, fy);  // dims 2l, 2l+1
        if (lane == 0)
            p[DIM] = (float)(((scnt[0] + scnt[1]) + scnt[2]) + scnt[3]);
    }
}

// ---------------- K3: per-cluster slice reduction + distance epilogue ----------------
__global__ __launch_bounds__(128)
void l2cc_final(const float* __restrict__ partial,
                const float* __restrict__ centers,
                float* __restrict__ out)
{
    const int c = blockIdx.x;     // 0..99
    const int t = threadIdx.x;    // 0..127 = dim

    float s = 0.0f, cnt = 0.0f;
    #pragma unroll
    for (int sl = 0; sl < NSLICE; ++sl) {
        const float* p = partial + (size_t)(c * NSLICE + sl) * PSTRIDE;
        s   += p[t];
        cnt += p[DIM];
    }

    const float centroid = s / fmaxf(cnt, 1.0f);
    const float dd = centers[c * DIM + t] - centroid;
    float sq = dd * dd;
    #pragma unroll
    for (int off = 32; off > 0; off >>= 1) sq += __shfl_xor(sq, off, 64);

    __shared__ float red[2];
    if ((t & 63) == 0) red[t >> 6] = sq;
    __syncthreads();
    if (t == 0) {
        const float total = red[0] + red[1];
        out[c] = (cnt > 0.0f && total > 0.0f) ? sqrtf(total) : 0.0f;
    }
}

extern "C" void kernel_launch(void* const* d_in, const int* in_sizes, int n_in,
                              void* d_out, int out_size, void* d_ws, size_t ws_size,
                              hipStream_t stream)
{
    const float* emb     = (const float*)d_in[0];  // [N, 128]
    const float* centers = (const float*)d_in[1];  // [100, 128]
    const float* logits  = (const float*)d_in[2];  // [N, 100]
    float* out = (float*)d_out;                    // [100]

    // workspace: assign [N ints, 4 MB] then partials [1600][130] f32 (~832 KB)
    int*   assign  = (int*)d_ws;
    float* partial = (float*)((char*)d_ws + (size_t)NROWS * sizeof(int));

    l2cc_argmax<<<(NROWS + 127) / 128, 256, 0, stream>>>(logits, assign);
    l2cc_gather<<<NCLS * NSLICE, 256, 0, stream>>>(emb, assign, partial);
    l2cc_final <<<NCLS, 128, 0, stream>>>(partial, centers, out);
}

// Round 10
// 197.561 us; speedup vs baseline: 1.1083x; 1.1083x over previous
//
#include <hip/hip_runtime.h>
#include <math.h>

// L2ClusterCentroid: N=1e6 rows, D=128, C=100.
// assign = argmax(logits, -1); centroids = segment_mean(embedding, assign);
// out[c] = counts[c]>0 ? ||centers[c] - centroids[c]||_2 : 0
//
// Round-10: round-9 (219us) = round-8 (191us) + {2-row/quad, tree-argmax,
// nontemporal}. Theory: the nt hints broke L2 merging of straddled 400B
// logits rows (75% of 64B segments straddle lines) -> fetch amplification.
// This round: round-9 structure with ALL nt hints removed (plain loads).

#define NROWS 1000000
#define DIM   128
#define NCLS  100
#define NSLICE 16
#define SLICE_ROWS (NROWS / NSLICE)   // 62500
#define PSTRIDE (DIM + 2)             // 130 floats (even -> float2-aligned)
#define QCAP  128
#define QMASK 127
#define DRAINN 16

typedef __attribute__((ext_vector_type(4))) float f32x4;
typedef __attribute__((ext_vector_type(2))) float f32x2;

// ---------------- K1: argmax over logits rows ----------------
__device__ __forceinline__ void row_argmax(const f32x4 v[6], float t, int p,
                                           int row, int* __restrict__ assign)
{
    // per-lane max over this lane's 25 cols (tree; nested triples -> v_max3)
    float m0 = fmaxf(fmaxf(v[0][0], v[0][1]), fmaxf(v[0][2], v[0][3]));
    float m1 = fmaxf(fmaxf(v[1][0], v[1][1]), fmaxf(v[1][2], v[1][3]));
    float m2 = fmaxf(fmaxf(v[2][0], v[2][1]), fmaxf(v[2][2], v[2][3]));
    float m3 = fmaxf(fmaxf(v[3][0], v[3][1]), fmaxf(v[3][2], v[3][3]));
    float m4 = fmaxf(fmaxf(v[4][0], v[4][1]), fmaxf(v[4][2], v[4][3]));
    float m5 = fmaxf(fmaxf(v[5][0], v[5][1]), fmaxf(v[5][2], v[5][3]));
    float mm = fmaxf(fmaxf(fmaxf(m0, m1), fmaxf(m2, m3)),
                     fmaxf(fmaxf(m4, m5), t));
    // quad value-merge (quad_perm DPP)
    mm = fmaxf(mm, __shfl_xor(mm, 1, 64));
    mm = fmaxf(mm, __shfl_xor(mm, 2, 64));
    // first index equal to max: min over matching cols (independent cmps)
    int bi = 0x7fffffff;
    #pragma unroll
    for (int i = 0; i < 6; ++i) {
        #pragma unroll
        for (int j = 0; j < 4; ++j) {
            const int col = 16 * i + 4 * p + j;
            if (v[i][j] == mm) bi = min(bi, col);
        }
    }
    if (t == mm) bi = min(bi, 96 + p);
    bi = min(bi, __shfl_xor(bi, 1, 64));
    bi = min(bi, __shfl_xor(bi, 2, 64));
    if (p == 0) assign[row] = bi;
}

__global__ __launch_bounds__(256)
void l2cc_argmax(const float* __restrict__ logits, int* __restrict__ assign)
{
    const int g = threadIdx.x >> 2;       // quad id 0..63
    const int p = threadIdx.x & 3;
    const int row0 = blockIdx.x * 128 + g * 2;   // 2 consecutive rows per quad
    if (row0 >= NROWS) return;                   // NROWS even -> row0+1 safe

    const f32x4* lr0 = reinterpret_cast<const f32x4*>(logits + (size_t)row0 * NCLS);
    const f32x4* lr1 = reinterpret_cast<const f32x4*>(logits + (size_t)(row0 + 1) * NCLS);

    f32x4 va[6], vb[6];
    #pragma unroll
    for (int i = 0; i < 6; ++i) va[i] = lr0[i * 4 + p];
    #pragma unroll
    for (int i = 0; i < 6; ++i) vb[i] = lr1[i * 4 + p];
    const float ta = logits[(size_t)row0 * NCLS + 96 + p];
    const float tb = logits[(size_t)(row0 + 1) * NCLS + 96 + p];

    row_argmax(va, ta, p, row0,     assign);
    row_argmax(vb, tb, p, row0 + 1, assign);
}

// ---------------- K2: scan + queued batch-gather ----------------
#define LDROW(R) *reinterpret_cast<const f32x2*>(emb + (size_t)(R) * DIM + lane * 2)

#define DRAIN16                                                              \
    {                                                                        \
        const int i0  = q[wave][(qhead+ 0)&QMASK], i1  = q[wave][(qhead+ 1)&QMASK]; \
        const int i2  = q[wave][(qhead+ 2)&QMASK], i3  = q[wave][(qhead+ 3)&QMASK]; \
        const int i4  = q[wave][(qhead+ 4)&QMASK], i5  = q[wave][(qhead+ 5)&QMASK]; \
        const int i6  = q[wave][(qhead+ 6)&QMASK], i7  = q[wave][(qhead+ 7)&QMASK]; \
        const int i8  = q[wave][(qhead+ 8)&QMASK], i9  = q[wave][(qhead+ 9)&QMASK]; \
        const int i10 = q[wave][(qhead+10)&QMASK], i11 = q[wave][(qhead+11)&QMASK]; \
        const int i12 = q[wave][(qhead+12)&QMASK], i13 = q[wave][(qhead+13)&QMASK]; \
        const int i14 = q[wave][(qhead+14)&QMASK], i15 = q[wave][(qhead+15)&QMASK]; \
        const f32x2 e0 = LDROW(i0),  e1 = LDROW(i1),  e2 = LDROW(i2),  e3 = LDROW(i3); \
        const f32x2 e4 = LDROW(i4),  e5 = LDROW(i5),  e6 = LDROW(i6),  e7 = LDROW(i7); \
        const f32x2 e8 = LDROW(i8),  e9 = LDROW(i9),  e10= LDROW(i10), e11= LDROW(i11);\
        const f32x2 e12= LDROW(i12), e13= LDROW(i13), e14= LDROW(i14), e15= LDROW(i15);\
        ax += e0[0];  ay += e0[1];  ax += e1[0];  ay += e1[1];               \
        ax += e2[0];  ay += e2[1];  ax += e3[0];  ay += e3[1];               \
        ax += e4[0];  ay += e4[1];  ax += e5[0];  ay += e5[1];               \
        ax += e6[0];  ay += e6[1];  ax += e7[0];  ay += e7[1];               \
        ax += e8[0];  ay += e8[1];  ax += e9[0];  ay += e9[1];               \
        ax += e10[0]; ay += e10[1]; ax += e11[0]; ay += e11[1];              \
        ax += e12[0]; ay += e12[1]; ax += e13[0]; ay += e13[1];              \
        ax += e14[0]; ay += e14[1]; ax += e15[0]; ay += e15[1];              \
        qhead += 16;                                                         \
    }

#define PUSH(AV, OFF)                                                        \
    {                                                                        \
        const unsigned long long m_ = __ballot((AV) == c);                   \
        if ((AV) == c) {                                                     \
            const int rank_ = __popcll(m_ & ((1ull << lane) - 1ull));        \
            q[wave][(qtail + rank_) & QMASK] = rw + (OFF) + lane;            \
        }                                                                    \
        const int pc_ = __popcll(m_);                                        \
        qtail += pc_; icnt += pc_;                                           \
        while (qtail - qhead >= DRAINN) DRAIN16                              \
    }

__global__ __launch_bounds__(256)
void l2cc_gather(const float* __restrict__ emb,
                 const int* __restrict__ assign,
                 float* __restrict__ partial)
{
    const int bid  = blockIdx.x;
    const int c    = bid / NSLICE;       // cluster this block owns
    const int sl   = bid - c * NSLICE;   // row-slice
    const int wave = threadIdx.x >> 6;
    const int lane = threadIdx.x & 63;

    __shared__ int   q[4][QCAP];         // per-wave matched-row-id ring
    __shared__ float sx[4][64], sy[4][64];
    __shared__ int   scnt[4];

    const int start = sl * SLICE_ROWS;
    const int end   = start + SLICE_ROWS;

    float ax = 0.0f, ay = 0.0f;
    int   icnt = 0, qhead = 0, qtail = 0;

    int rw = start + wave * 256;
    int a0 = (rw +   0 + lane < end) ? assign[rw +   0 + lane] : -1;
    int a1 = (rw +  64 + lane < end) ? assign[rw +  64 + lane] : -1;
    int a2 = (rw + 128 + lane < end) ? assign[rw + 128 + lane] : -1;
    int a3 = (rw + 192 + lane < end) ? assign[rw + 192 + lane] : -1;

    for (; rw < end; rw += 1024) {
        const int rn = rw + 1024;        // prefetch next 256-row group
        int b0 = -1, b1 = -1, b2 = -1, b3 = -1;
        if (rn < end) {
            b0 = (rn +   0 + lane < end) ? assign[rn +   0 + lane] : -1;
            b1 = (rn +  64 + lane < end) ? assign[rn +  64 + lane] : -1;
            b2 = (rn + 128 + lane < end) ? assign[rn + 128 + lane] : -1;
            b3 = (rn + 192 + lane < end) ? assign[rn + 192 + lane] : -1;
        }

        PUSH(a0, 0) PUSH(a1, 64) PUSH(a2, 128) PUSH(a3, 192)

        a0 = b0; a1 = b1; a2 = b2; a3 = b3;
    }

    // tail: drain remaining queued rows one at a time (fixed order)
    while (qtail > qhead) {
        const int r = q[wave][qhead & QMASK]; ++qhead;
        const f32x2 e = LDROW(r);
        ax += e[0]; ay += e[1];
    }

    // cross-wave reduce (fixed order, deterministic)
    sx[wave][lane] = ax;
    sy[wave][lane] = ay;
    if (lane == 0) scnt[wave] = icnt;
    __syncthreads();
    if (wave == 0) {
        const float fx = ((sx[0][lane] + sx[1][lane]) + sx[2][lane]) + sx[3][lane];
        const float fy = ((sy[0][lane] + sy[1][lane]) + sy[2][lane]) + sy[3][lane];
        float* p = partial + (size_t)bid * PSTRIDE;
        reinterpret_cast<float2*>(p)[lane] = make_float2(fx, fy);  // dims 2l, 2l+1
        if (lane == 0)
            p[DIM] = (float)(((scnt[0] + scnt[1]) + scnt[2]) + scnt[3]);
    }
}

// ---------------- K3: per-cluster slice reduction + distance epilogue ----------------
__global__ __launch_bounds__(128)
void l2cc_final(const float* __restrict__ partial,
                const float* __restrict__ centers,
                float* __restrict__ out)
{
    const int c = blockIdx.x;     // 0..99
    const int t = threadIdx.x;    // 0..127 = dim

    float s = 0.0f, cnt = 0.0f;
    #pragma unroll
    for (int sl = 0; sl < NSLICE; ++sl) {
        const float* p = partial + (size_t)(c * NSLICE + sl) * PSTRIDE;
        s   += p[t];
        cnt += p[DIM];
    }

    const float centroid = s / fmaxf(cnt, 1.0f);
    const float dd = centers[c * DIM + t] - centroid;
    float sq = dd * dd;
    #pragma unroll
    for (int off = 32; off > 0; off >>= 1) sq += __shfl_xor(sq, off, 64);

    __shared__ float red[2];
    if ((t & 63) == 0) red[t >> 6] = sq;
    __syncthreads();
    if (t == 0) {
        const float total = red[0] + red[1];
        out[c] = (cnt > 0.0f && total > 0.0f) ? sqrtf(total) : 0.0f;
    }
}

extern "C" void kernel_launch(void* const* d_in, const int* in_sizes, int n_in,
                              void* d_out, int out_size, void* d_ws, size_t ws_size,
                              hipStream_t stream)
{
    const float* emb     = (const float*)d_in[0];  // [N, 128]
    const float* centers = (const float*)d_in[1];  // [100, 128]
    const float* logits  = (const float*)d_in[2];  // [N, 100]
    float* out = (float*)d_out;                    // [100]

    // workspace: assign [N ints, 4 MB] then partials [1600][130] f32 (~832 KB)
    int*   assign  = (int*)d_ws;
    float* partial = (float*)((char*)d_ws + (size_t)NROWS * sizeof(int));

    l2cc_argmax<<<(NROWS + 127) / 128, 256, 0, stream>>>(logits, assign);
    l2cc_gather<<<NCLS * NSLICE, 256, 0, stream>>>(emb, assign, partial);
    l2cc_final <<<NCLS, 128, 0, stream>>>(partial, centers, out);
}

// Round 11
// 183.974 us; speedup vs baseline: 1.1902x; 1.0739x over previous
//
#include <hip/hip_runtime.h>
#include <math.h>

// L2ClusterCentroid: N=1e6 rows, D=128, C=100.
// assign = argmax(logits, -1); centroids = segment_mean(embedding, assign);
// out[c] = counts[c]>0 ? ||centers[c] - centroids[c]||_2 : 0
//
// Round-11: K1 reverted to exact round-8 form (proven fastest; round-9/10
// restructure was neutral-to-negative). K2 drains widened to 16B/lane:
// each drain instruction covers TWO queued rows (half-wave per row, f32x4
// per lane) -> half the VMEM instructions, 1KB per wave-load. Partial layout
// now linear dims (no permute), PSTRIDE 132 for 16B alignment.

#define NROWS 1000000
#define DIM   128
#define NCLS  100
#define NSLICE 16
#define SLICE_ROWS (NROWS / NSLICE)   // 62500
#define PSTRIDE 132                   // 128 dims + count + pad (528 B, 16B-aligned)
#define QCAP  128
#define QMASK 127

typedef __attribute__((ext_vector_type(4))) float f32x4;

// ---------------- K1: argmax over logits rows (exact round-8 form) ----------------
__global__ __launch_bounds__(256)
void l2cc_argmax(const float* __restrict__ logits, int* __restrict__ assign)
{
    const int tid = threadIdx.x;
    const int row = blockIdx.x * 64 + (tid >> 2);
    const int p   = tid & 3;
    if (row >= NROWS) return;

    const float4* lrow = reinterpret_cast<const float4*>(logits + (size_t)row * NCLS);
    float best = -INFINITY;
    int   bi   = 0x7fffffff;
    #pragma unroll
    for (int i = 0; i < 6; ++i) {
        const float4 v = lrow[i * 4 + p];       // cols 16i+4p .. +3
        const int c0 = i * 16 + p * 4;
        if (v.x > best) { best = v.x; bi = c0;     }
        if (v.y > best) { best = v.y; bi = c0 + 1; }
        if (v.z > best) { best = v.z; bi = c0 + 2; }
        if (v.w > best) { best = v.w; bi = c0 + 3; }
    }
    {   // tail cols 96..99
        const float t = logits[(size_t)row * NCLS + 96 + p];
        if (t > best) { best = t; bi = 96 + p; }
    }
    #pragma unroll
    for (int off = 1; off <= 2; off <<= 1) {    // quad_perm DPP merge
        const float ov = __shfl_xor(best, off, 64);
        const int   oi = __shfl_xor(bi,   off, 64);
        if (ov > best || (ov == best && oi < bi)) { best = ov; bi = oi; }
    }
    if (p == 0) assign[row] = bi;
}

// ---------------- K2: scan + queued batch-gather (16B/lane drains) ----------------
// Drain 16 queued rows as 8 wave-instructions: lanes 0-31 take row 2k,
// lanes 32-63 take row 2k+1; each lane loads f32x4 = dims l5*4..+3.
#define DRAIN16                                                               \
    {                                                                         \
        _Pragma("unroll")                                                     \
        for (int k_ = 0; k_ < 8; ++k_) {                                      \
            const int r_ = q[wave][(qhead + 2 * k_ + half) & QMASK];          \
            acc += *reinterpret_cast<const f32x4*>(                           \
                emb + (size_t)r_ * DIM + l5 * 4);                             \
        }                                                                     \
        qhead += 16;                                                          \
    }

#define PUSH(AV, OFF)                                                         \
    {                                                                         \
        const unsigned long long m_ = __ballot((AV) == c);                    \
        if ((AV) == c) {                                                      \
            const int rank_ = __popcll(m_ & ((1ull << lane) - 1ull));         \
            q[wave][(qtail + rank_) & QMASK] = rw + (OFF) + lane;             \
        }                                                                     \
        const int pc_ = __popcll(m_);                                         \
        qtail += pc_; icnt += pc_;                                            \
        while (qtail - qhead >= 16) DRAIN16                                   \
    }

__global__ __launch_bounds__(256)
void l2cc_gather(const float* __restrict__ emb,
                 const int* __restrict__ assign,
                 float* __restrict__ partial)
{
    const int bid  = blockIdx.x;
    const int c    = bid / NSLICE;       // cluster this block owns
    const int sl   = bid - c * NSLICE;   // row-slice
    const int wave = threadIdx.x >> 6;
    const int lane = threadIdx.x & 63;
    const int half = lane >> 5;          // 0: even queue slot, 1: odd
    const int l5   = lane & 31;          // dim-quad index within row

    __shared__ int   q[4][QCAP];         // per-wave matched-row-id ring
    __shared__ f32x4 sacc[4][64];        // per-wave per-lane dim sums (4 KB)
    __shared__ int   scnt[4];

    const int start = sl * SLICE_ROWS;
    const int end   = start + SLICE_ROWS;

    f32x4 acc = {0.0f, 0.0f, 0.0f, 0.0f};
    int   icnt = 0, qhead = 0, qtail = 0;

    int rw = start + wave * 256;
    int a0 = (rw +   0 + lane < end) ? assign[rw +   0 + lane] : -1;
    int a1 = (rw +  64 + lane < end) ? assign[rw +  64 + lane] : -1;
    int a2 = (rw + 128 + lane < end) ? assign[rw + 128 + lane] : -1;
    int a3 = (rw + 192 + lane < end) ? assign[rw + 192 + lane] : -1;

    for (; rw < end; rw += 1024) {
        const int rn = rw + 1024;        // prefetch next 256-row group
        int b0 = -1, b1 = -1, b2 = -1, b3 = -1;
        if (rn < end) {
            b0 = (rn +   0 + lane < end) ? assign[rn +   0 + lane] : -1;
            b1 = (rn +  64 + lane < end) ? assign[rn +  64 + lane] : -1;
            b2 = (rn + 128 + lane < end) ? assign[rn + 128 + lane] : -1;
            b3 = (rn + 192 + lane < end) ? assign[rn + 192 + lane] : -1;
        }

        PUSH(a0, 0) PUSH(a1, 64) PUSH(a2, 128) PUSH(a3, 192)

        a0 = b0; a1 = b1; a2 = b2; a3 = b3;
    }

    // tail: remaining queued rows, one at a time (half-wave active)
    while (qtail > qhead) {
        const int r = q[wave][qhead & QMASK]; ++qhead;
        if (half == 0)
            acc += *reinterpret_cast<const f32x4*>(emb + (size_t)r * DIM + l5 * 4);
    }

    // cross-wave/half reduce (fixed order, deterministic)
    sacc[wave][lane] = acc;
    if (lane == 0) scnt[wave] = icnt;
    __syncthreads();
    if (wave == 0 && lane < 32) {
        f32x4 v = (((sacc[0][lane] + sacc[1][lane]) + sacc[2][lane]) + sacc[3][lane])
                + (((sacc[0][32 + lane] + sacc[1][32 + lane])
                  + sacc[2][32 + lane]) + sacc[3][32 + lane]);
        float* p = partial + (size_t)bid * PSTRIDE;
        *reinterpret_cast<f32x4*>(p + lane * 4) = v;       // dims 4l..4l+3 (linear)
        if (lane == 0)
            p[DIM] = (float)(((scnt[0] + scnt[1]) + scnt[2]) + scnt[3]);
    }
}

// ---------------- K3: per-cluster slice reduction + distance epilogue ----------------
__global__ __launch_bounds__(128)
void l2cc_final(const float* __restrict__ partial,
                const float* __restrict__ centers,
                float* __restrict__ out)
{
    const int c = blockIdx.x;     // 0..99
    const int t = threadIdx.x;    // 0..127 = dim (linear layout now)

    float s = 0.0f, cnt = 0.0f;
    #pragma unroll
    for (int sl = 0; sl < NSLICE; ++sl) {
        const float* p = partial + (size_t)(c * NSLICE + sl) * PSTRIDE;
        s   += p[t];
        cnt += p[DIM];
    }

    const float centroid = s / fmaxf(cnt, 1.0f);
    const float dd = centers[c * DIM + t] - centroid;
    float sq = dd * dd;
    #pragma unroll
    for (int off = 32; off > 0; off >>= 1) sq += __shfl_xor(sq, off, 64);

    __shared__ float red[2];
    if ((t & 63) == 0) red[t >> 6] = sq;
    __syncthreads();
    if (t == 0) {
        const float total = red[0] + red[1];
        out[c] = (cnt > 0.0f && total > 0.0f) ? sqrtf(total) : 0.0f;
    }
}

extern "C" void kernel_launch(void* const* d_in, const int* in_sizes, int n_in,
                              void* d_out, int out_size, void* d_ws, size_t ws_size,
                              hipStream_t stream)
{
    const float* emb     = (const float*)d_in[0];  // [N, 128]
    const float* centers = (const float*)d_in[1];  // [100, 128]
    const float* logits  = (const float*)d_in[2];  // [N, 100]
    float* out = (float*)d_out;                    // [100]

    // workspace: assign [N ints, 4 MB] then partials [1600][132] f32 (~845 KB)
    int*   assign  = (int*)d_ws;
    float* partial = (float*)((char*)d_ws + (size_t)NROWS * sizeof(int));

    l2cc_argmax<<<(NROWS + 63) / 64, 256, 0, stream>>>(logits, assign);
    l2cc_gather<<<NCLS * NSLICE, 256, 0, stream>>>(emb, assign, partial);
    l2cc_final <<<NCLS, 128, 0, stream>>>(partial, centers, out);
}